// Round 1
// baseline (3097.240 us; speedup 1.0000x reference)
//
#include <hip/hip_runtime.h>
#include <math.h>

#define NB 128
#define NC 256
#define NM 784
constexpr size_t MAT  = (size_t)NC * NC;   // 65536
constexpr size_t MATB = MAT * NB;          // 8388608 floats per buffer

// ---------------- per-row mean over M ----------------
__global__ __launch_bounds__(256) void mean_kernel(const float* __restrict__ x,
                                                   float* __restrict__ mean) {
    int row = blockIdx.x;                       // 0..NB*NC-1
    const float* xr = x + (size_t)row * NM;
    int tid = threadIdx.x;
    float s = 0.f;
    for (int m = tid; m < NM; m += 256) s += xr[m];
    for (int off = 32; off; off >>= 1) s += __shfl_down(s, off);
    __shared__ float red[4];
    if ((tid & 63) == 0) red[tid >> 6] = s;
    __syncthreads();
    if (tid == 0) mean[row] = (red[0] + red[1] + red[2] + red[3]) / (float)NM;
}

// ---------------- covariance: C = xc @ xc^T / M ----------------
__global__ __launch_bounds__(256) void cov_kernel(const float* __restrict__ x,
                                                  const float* __restrict__ mean,
                                                  float* __restrict__ C) {
    int tile = blockIdx.x;
    int b = tile >> 4, t = tile & 15;
    int m0 = (t >> 2) * 64, n0 = (t & 3) * 64;
    const float* xb = x + (size_t)b * NC * NM;
    const float* mb = mean + b * NC;
    __shared__ float As[16][64];
    __shared__ float Bs[16][64];
    int tid = threadIdx.x;
    int lam = tid >> 2, lak = (tid & 3) * 4;    // A-load: row m0+lam, 4 k's
    int lbj = tid & 63, lbk = (tid >> 6) * 4;   // B-load: row n0+lbj, 4 k's
    int tm = (tid >> 4) * 4, tn = (tid & 15) * 4;
    float amean = mb[m0 + lam];
    float bmean = mb[n0 + lbj];
    float acc[4][4] = {};
    for (int k0 = 0; k0 < NM; k0 += 16) {       // 784 = 49*16
        float4 av = *(const float4*)&xb[(size_t)(m0 + lam) * NM + k0 + lak];
        float4 bv = *(const float4*)&xb[(size_t)(n0 + lbj) * NM + k0 + lbk];
        __syncthreads();
        As[lak + 0][lam] = av.x - amean;
        As[lak + 1][lam] = av.y - amean;
        As[lak + 2][lam] = av.z - amean;
        As[lak + 3][lam] = av.w - amean;
        Bs[lbk + 0][lbj] = bv.x - bmean;
        Bs[lbk + 1][lbj] = bv.y - bmean;
        Bs[lbk + 2][lbj] = bv.z - bmean;
        Bs[lbk + 3][lbj] = bv.w - bmean;
        __syncthreads();
        #pragma unroll
        for (int kk = 0; kk < 16; ++kk) {
            const float4 aq = *(const float4*)&As[kk][tm];
            const float4 bq = *(const float4*)&Bs[kk][tn];
            float aa[4] = {aq.x, aq.y, aq.z, aq.w};
            float bb[4] = {bq.x, bq.y, bq.z, bq.w};
            #pragma unroll
            for (int i = 0; i < 4; ++i)
                #pragma unroll
                for (int j = 0; j < 4; ++j)
                    acc[i][j] = fmaf(aa[i], bb[j], acc[i][j]);
        }
    }
    const float inv = 1.0f / (float)NM;
    size_t bofs = (size_t)b * MAT;
    #pragma unroll
    for (int i = 0; i < 4; ++i)
        #pragma unroll
        for (int j = 0; j < 4; ++j)
            C[bofs + (size_t)(m0 + tm + i) * NC + (n0 + tn + j)] = acc[i][j] * inv;
}

// ---------------- batched GEMM with epilogue ----------------
// C = alpha*(scaleA?scaleA[b]:1)*(A@B) + gamma*I + b1*M1 + b2*M2
__global__ __launch_bounds__(256) void bgemm_kernel(const float* __restrict__ A,
                                                    const float* __restrict__ B,
                                                    float* __restrict__ C,
                                                    const float* __restrict__ scaleA,
                                                    float alpha, float gamma,
                                                    const float* __restrict__ M1, float b1,
                                                    const float* __restrict__ M2, float b2) {
    int tile = blockIdx.x;
    int b = tile >> 4, t = tile & 15;
    int m0 = (t >> 2) * 64, n0 = (t & 3) * 64;
    size_t bofs = (size_t)b * MAT;
    const float* Ab = A + bofs;
    const float* Bb = B + bofs;
    __shared__ float As[16][64];
    __shared__ float Bs[16][64];
    int tid = threadIdx.x;
    int lam = tid >> 2, lak = (tid & 3) * 4;
    int lbk = tid >> 4, lbn = (tid & 15) * 4;
    int tm = (tid >> 4) * 4, tn = (tid & 15) * 4;
    float acc[4][4] = {};
    for (int k0 = 0; k0 < NC; k0 += 16) {
        float4 av = *(const float4*)&Ab[(size_t)(m0 + lam) * NC + k0 + lak];
        float4 bv = *(const float4*)&Bb[(size_t)(k0 + lbk) * NC + n0 + lbn];
        __syncthreads();
        As[lak + 0][lam] = av.x;
        As[lak + 1][lam] = av.y;
        As[lak + 2][lam] = av.z;
        As[lak + 3][lam] = av.w;
        *(float4*)&Bs[lbk][lbn] = bv;
        __syncthreads();
        #pragma unroll
        for (int kk = 0; kk < 16; ++kk) {
            const float4 aq = *(const float4*)&As[kk][tm];
            const float4 bq = *(const float4*)&Bs[kk][tn];
            float aa[4] = {aq.x, aq.y, aq.z, aq.w};
            float bb[4] = {bq.x, bq.y, bq.z, bq.w};
            #pragma unroll
            for (int i = 0; i < 4; ++i)
                #pragma unroll
                for (int j = 0; j < 4; ++j)
                    acc[i][j] = fmaf(aa[i], bb[j], acc[i][j]);
        }
    }
    float s = alpha * (scaleA ? scaleA[b] : 1.0f);
    #pragma unroll
    for (int i = 0; i < 4; ++i) {
        int gi = m0 + tm + i;
        #pragma unroll
        for (int j = 0; j < 4; ++j) {
            int gj = n0 + tn + j;
            size_t o = bofs + (size_t)gi * NC + gj;
            float v = acc[i][j] * s;
            if (gi == gj) v += gamma;
            if (M1) v = fmaf(b1, M1[o], v);
            if (M2) v = fmaf(b2, M2[o], v);
            C[o] = v;
        }
    }
}

// ---------------- trace -> 1/tr and sqrt(tr) ----------------
__global__ __launch_bounds__(256) void trace_kernel(const float* __restrict__ C,
                                                    float* __restrict__ rnorm,
                                                    float* __restrict__ snorm) {
    int b = blockIdx.x;
    int tid = threadIdx.x;
    float v = C[(size_t)b * MAT + (size_t)tid * NC + tid];
    for (int off = 32; off; off >>= 1) v += __shfl_down(v, off);
    __shared__ float red[4];
    if ((tid & 63) == 0) red[tid >> 6] = v;
    __syncthreads();
    if (tid == 0) {
        float tr = red[0] + red[1] + red[2] + red[3];
        rnorm[b] = 1.0f / tr;
        snorm[b] = sqrtf(tr);
    }
}

// ---------------- 1/sqrt(clip(diag,eps)) ----------------
__global__ __launch_bounds__(256) void istd_kernel(const float* __restrict__ S,
                                                   float* __restrict__ istd) {
    int b = blockIdx.x;
    int tid = threadIdx.x;
    float d = S[(size_t)b * MAT + (size_t)tid * NC + tid];
    d = fmaxf(d, 1.1920929e-7f);
    istd[b * NC + tid] = 1.0f / sqrtf(d);
}

// ---------------- out = 1.5*I - 0.5*scale_b*in ----------------
__global__ __launch_bounds__(256) void ew_z1_kernel(const float* __restrict__ in,
                                                    float* __restrict__ out,
                                                    const float* __restrict__ scale) {
    size_t idx = (size_t)blockIdx.x * 256 + threadIdx.x;
    int b = (int)(idx >> 16);
    int ij = (int)(idx & 65535);
    float sc = scale ? scale[b] : 1.0f;
    float v = -0.5f * sc * in[idx];
    if ((ij >> 8) == (ij & 255)) v += 1.5f;
    out[idx] = v;
}

// ---------------- out = in * istd_i * istd_j * (1/1.2) ----------------
__global__ __launch_bounds__(256) void ew_corr_kernel(const float* __restrict__ in,
                                                      float* __restrict__ out,
                                                      const float* __restrict__ istd) {
    size_t idx = (size_t)blockIdx.x * 256 + threadIdx.x;
    int b = (int)(idx >> 16);
    int ij = (int)(idx & 65535);
    int i = ij >> 8, j = ij & 255;
    out[idx] = in[idx] * istd[b * NC + i] * istd[b * NC + j] * (1.0f / 1.2f);
}

// ---------------- out = a*X + b*Y ----------------
__global__ __launch_bounds__(256) void ew_axpy2_kernel(const float* __restrict__ X,
                                                       const float* __restrict__ Y,
                                                       float* __restrict__ out,
                                                       float a, float b) {
    size_t idx = (size_t)blockIdx.x * 256 + threadIdx.x;
    out[idx] = fmaf(a, X[idx], b * Y[idx]);
}

// ---------------- W[b,i,i] -= 1 ----------------
__global__ __launch_bounds__(256) void subdiag_kernel(float* __restrict__ W) {
    W[(size_t)blockIdx.x * MAT + (size_t)threadIdx.x * NC + threadIdx.x] -= 1.0f;
}

// ---------------- triuvec output: out = (r==c) ? 0 : 4*R[r,c] ----------------
__global__ __launch_bounds__(256) void out_kernel(const float* __restrict__ R,
                                                  float* __restrict__ out) {
    int blk = blockIdx.x;            // b*NC + r
    int b = blk >> 8, r = blk & 255;
    int c = threadIdx.x;
    if (c < r) return;
    size_t rowoff = (size_t)r * NC - ((size_t)r * (r - 1)) / 2;
    float v = (c == r) ? 0.f : 4.f * R[(size_t)b * MAT + (size_t)r * NC + c];
    out[(size_t)b * 32896 + rowoff + (c - r)] = v;
}

extern "C" void kernel_launch(void* const* d_in, const int* in_sizes, int n_in,
                              void* d_out, int out_size, void* d_ws, size_t ws_size,
                              hipStream_t stream) {
    const float* x = (const float*)d_in[0];
    float* out = (float*)d_out;
    float* W0 = (float*)d_ws;
    float* W1 = W0 + MATB;
    float* W2 = W1 + MATB;
    float* W3 = W2 + MATB;
    float* mean  = W3 + MATB;        // NB*NC
    float* istd  = mean + NB * NC;   // NB*NC
    float* rnorm = istd + NB * NC;   // NB
    float* snorm = rnorm + NB;       // NB

    const int EWG = (int)(MATB / 256);   // 32768

    auto GEMM = [&](const float* A, const float* B, float* C, const float* sA,
                    float alpha, float gamma, const float* M1 = nullptr, float b1 = 0.f,
                    const float* M2 = nullptr, float b2 = 0.f) {
        bgemm_kernel<<<NB * 16, 256, 0, stream>>>(A, B, C, sA, alpha, gamma, M1, b1, M2, b2);
    };

    // ---- covariance pooling ----
    mean_kernel<<<NB * NC, 256, 0, stream>>>(x, mean);
    cov_kernel<<<NB * 16, 256, 0, stream>>>(x, mean, W0);       // cov -> W0
    trace_kernel<<<NB, 256, 0, stream>>>(W0, rnorm, snorm);

    // ---- reference NS5 sqrt (trace-normalized, 5 iterations) ----
    ew_z1_kernel<<<EWG, 256, 0, stream>>>(W0, W1, rnorm);       // Z1 = 1.5I - 0.5*An -> W1
    GEMM(W0, W1, W2, rnorm, 1.f, 0.f);                          // Y1 = An@Z1 -> W2
    // loop 1 (Y=W2,Z=W1)
    GEMM(W1, W2, W3, nullptr, -0.5f, 1.5f);                     // T -> W3
    GEMM(W2, W3, W0, nullptr, 1.f, 0.f);                        // Y -> W0
    GEMM(W3, W1, W2, nullptr, 1.f, 0.f);                        // Z -> W2
    // loop 2 (Y=W0,Z=W2)
    GEMM(W2, W0, W1, nullptr, -0.5f, 1.5f);                     // T -> W1
    GEMM(W0, W1, W3, nullptr, 1.f, 0.f);                        // Y -> W3
    GEMM(W1, W2, W0, nullptr, 1.f, 0.f);                        // Z -> W0
    // loop 3 (Y=W3,Z=W0)
    GEMM(W0, W3, W1, nullptr, -0.5f, 1.5f);                     // T -> W1
    GEMM(W3, W1, W2, nullptr, 1.f, 0.f);                        // Y -> W2
    GEMM(W1, W0, W3, nullptr, 1.f, 0.f);                        // Z -> W3
    // final: s = 0.5*Y@(3I - Z@Y)*sqrt(tr)  (Y=W2,Z=W3)
    GEMM(W3, W2, W0, nullptr, -1.f, 3.f);                       // Tf -> W0
    GEMM(W2, W0, W1, snorm, 0.5f, 0.f);                         // s -> W1

    // ---- correlation normalization, safety scale 1/1.2 ----
    istd_kernel<<<NB, 256, 0, stream>>>(W1, istd);
    ew_corr_kernel<<<EWG, 256, 0, stream>>>(W1, W2, istd);      // A0 = Ccorr/1.2 -> W2

    // ---- NS sqrt of A0: C1 = sqrt(A0), 8 coupled updates ----
    ew_z1_kernel<<<EWG, 256, 0, stream>>>(W2, W0, nullptr);     // Z1 -> W0
    GEMM(W2, W0, W1, nullptr, 1.f, 0.f);                        // Y1 -> W1   (Y=W1,Z=W0)
    // update 2
    GEMM(W0, W1, W2, nullptr, -0.5f, 1.5f);                     // T -> W2
    GEMM(W1, W2, W3, nullptr, 1.f, 0.f);                        // Y -> W3
    GEMM(W2, W0, W1, nullptr, 1.f, 0.f);                        // Z -> W1   (Y=W3,Z=W1)
    // update 3
    GEMM(W1, W3, W0, nullptr, -0.5f, 1.5f);                     // T -> W0
    GEMM(W3, W0, W2, nullptr, 1.f, 0.f);                        // Y -> W2
    GEMM(W0, W1, W3, nullptr, 1.f, 0.f);                        // Z -> W3   (Y=W2,Z=W3)
    // update 4
    GEMM(W3, W2, W0, nullptr, -0.5f, 1.5f);
    GEMM(W2, W0, W1, nullptr, 1.f, 0.f);
    GEMM(W0, W3, W2, nullptr, 1.f, 0.f);                        // (Y=W1,Z=W2)
    // update 5
    GEMM(W2, W1, W0, nullptr, -0.5f, 1.5f);
    GEMM(W1, W0, W3, nullptr, 1.f, 0.f);
    GEMM(W0, W2, W1, nullptr, 1.f, 0.f);                        // (Y=W3,Z=W1)
    // update 6
    GEMM(W1, W3, W0, nullptr, -0.5f, 1.5f);
    GEMM(W3, W0, W2, nullptr, 1.f, 0.f);
    GEMM(W0, W1, W3, nullptr, 1.f, 0.f);                        // (Y=W2,Z=W3)
    // update 7
    GEMM(W3, W2, W0, nullptr, -0.5f, 1.5f);
    GEMM(W2, W0, W1, nullptr, 1.f, 0.f);
    GEMM(W0, W3, W2, nullptr, 1.f, 0.f);                        // (Y=W1,Z=W2)
    // update 8 (Z not needed)
    GEMM(W2, W1, W0, nullptr, -0.5f, 1.5f);                     // T -> W0
    GEMM(W1, W0, W3, nullptr, 1.f, 0.f);                        // C1 -> W3

    // ---- log(C1) = log(I+E), degree-16 Mercator via Paterson-Stockmeyer ----
    subdiag_kernel<<<NB, 256, 0, stream>>>(W3);                 // E = C1 - I (in W3)
    GEMM(W3, W3, W0, nullptr, 1.f, 0.f);                        // E2 -> W0
    ew_axpy2_kernel<<<EWG, 256, 0, stream>>>(W3, W0, W1, 1.f / 15.f, -1.f / 16.f); // R -> W1
    GEMM(W1, W0, W2, nullptr, 1.f, 0.f, W3, 1.f / 13.f, W0, -1.f / 14.f);
    GEMM(W2, W0, W1, nullptr, 1.f, 0.f, W3, 1.f / 11.f, W0, -1.f / 12.f);
    GEMM(W1, W0, W2, nullptr, 1.f, 0.f, W3, 1.f / 9.f,  W0, -1.f / 10.f);
    GEMM(W2, W0, W1, nullptr, 1.f, 0.f, W3, 1.f / 7.f,  W0, -1.f / 8.f);
    GEMM(W1, W0, W2, nullptr, 1.f, 0.f, W3, 1.f / 5.f,  W0, -1.f / 6.f);
    GEMM(W2, W0, W1, nullptr, 1.f, 0.f, W3, 1.f / 3.f,  W0, -1.f / 4.f);
    GEMM(W1, W0, W2, nullptr, 1.f, 0.f, W3, 1.f,        W0, -1.f / 2.f);  // log(C1) -> W2

    // ---- output: triu of 2*logC0 = 4*log(C1) off-diag, 0 diag ----
    out_kernel<<<NB * NC, 256, 0, stream>>>(W2, out);
}

// Round 2
// 1630.000 us; speedup vs baseline: 1.9001x; 1.9001x over previous
//
#include <hip/hip_runtime.h>
#include <math.h>

#define NB 128
#define NC 256
#define NM 784
constexpr size_t MAT  = (size_t)NC * NC;   // 65536
constexpr size_t MATB = MAT * NB;          // 8388608 floats per buffer

typedef _Float16 half8 __attribute__((ext_vector_type(8)));
typedef float f4 __attribute__((ext_vector_type(4)));

// ---------------- per-row mean over M ----------------
__global__ __launch_bounds__(256) void mean_kernel(const float* __restrict__ x,
                                                   float* __restrict__ mean) {
    int row = blockIdx.x;                       // 0..NB*NC-1
    const float* xr = x + (size_t)row * NM;
    int tid = threadIdx.x;
    float s = 0.f;
    for (int m = tid; m < NM; m += 256) s += xr[m];
    for (int off = 32; off; off >>= 1) s += __shfl_down(s, off);
    __shared__ float red[4];
    if ((tid & 63) == 0) red[tid >> 6] = s;
    __syncthreads();
    if (tid == 0) mean[row] = (red[0] + red[1] + red[2] + red[3]) / (float)NM;
}

// ---------------- covariance: C = xc @ xc^T / M ----------------
__global__ __launch_bounds__(256) void cov_kernel(const float* __restrict__ x,
                                                  const float* __restrict__ mean,
                                                  float* __restrict__ C) {
    int tile = blockIdx.x;
    int b = tile >> 4, t = tile & 15;
    int m0 = (t >> 2) * 64, n0 = (t & 3) * 64;
    const float* xb = x + (size_t)b * NC * NM;
    const float* mb = mean + b * NC;
    __shared__ float As[16][64];
    __shared__ float Bs[16][64];
    int tid = threadIdx.x;
    int lam = tid >> 2, lak = (tid & 3) * 4;
    int lbj = tid & 63, lbk = (tid >> 6) * 4;
    int tm = (tid >> 4) * 4, tn = (tid & 15) * 4;
    float amean = mb[m0 + lam];
    float bmean = mb[n0 + lbj];
    float acc[4][4] = {};
    for (int k0 = 0; k0 < NM; k0 += 16) {
        float4 av = *(const float4*)&xb[(size_t)(m0 + lam) * NM + k0 + lak];
        float4 bv = *(const float4*)&xb[(size_t)(n0 + lbj) * NM + k0 + lbk];
        __syncthreads();
        As[lak + 0][lam] = av.x - amean;
        As[lak + 1][lam] = av.y - amean;
        As[lak + 2][lam] = av.z - amean;
        As[lak + 3][lam] = av.w - amean;
        Bs[lbk + 0][lbj] = bv.x - bmean;
        Bs[lbk + 1][lbj] = bv.y - bmean;
        Bs[lbk + 2][lbj] = bv.z - bmean;
        Bs[lbk + 3][lbj] = bv.w - bmean;
        __syncthreads();
        #pragma unroll
        for (int kk = 0; kk < 16; ++kk) {
            const float4 aq = *(const float4*)&As[kk][tm];
            const float4 bq = *(const float4*)&Bs[kk][tn];
            float aa[4] = {aq.x, aq.y, aq.z, aq.w};
            float bb[4] = {bq.x, bq.y, bq.z, bq.w};
            #pragma unroll
            for (int i = 0; i < 4; ++i)
                #pragma unroll
                for (int j = 0; j < 4; ++j)
                    acc[i][j] = fmaf(aa[i], bb[j], acc[i][j]);
        }
    }
    const float inv = 1.0f / (float)NM;
    size_t bofs = (size_t)b * MAT;
    #pragma unroll
    for (int i = 0; i < 4; ++i)
        #pragma unroll
        for (int j = 0; j < 4; ++j)
            C[bofs + (size_t)(m0 + tm + i) * NC + (n0 + tn + j)] = acc[i][j] * inv;
}

// ---------------- batched GEMM via split-fp16 MFMA ----------------
// C = alpha*(scaleA?scaleA[b]:1)*(A@B) + gamma*I + b1*M1 + b2*M2
__global__ __launch_bounds__(256, 2) void mfma_bgemm_kernel(const float* __restrict__ A,
                                                            const float* __restrict__ B,
                                                            float* __restrict__ C,
                                                            const float* __restrict__ scaleA,
                                                            float alpha, float gamma,
                                                            const float* __restrict__ M1, float b1,
                                                            const float* __restrict__ M2, float b2) {
    __shared__ alignas(16) char lds[65536];
    const int AH = 0, AL = 16384, BH = 32768, BL = 49152;
    int bid = blockIdx.x;
    int b = bid >> 2, q = bid & 3;
    int bm0 = (q >> 1) * 128, bn0 = (q & 1) * 128;
    size_t bofs = (size_t)b * MAT;
    const float* Ab = A + bofs;
    const float* Bb = B + bofs;
    int tid = threadIdx.x;
    int w = tid >> 6, l = tid & 63;
    int wm = (w >> 1) * 64, wn = (w & 1) * 64;
    int lr = l & 15;              // frag row/col within 16
    int lk = (l >> 4) * 8;        // frag k-offset
    f4 acc[4][4] = {};

    for (int t = 0; t < 4; ++t) {
        int k0 = t * 64;
        if (t) __syncthreads();
        // ---- stage A tile [128 rows][64 k] -> As hi/lo (swizzled) ----
        #pragma unroll
        for (int p = 0; p < 4; ++p) {
            int f = p * 256 + tid;
            int m = f >> 3, ks = (f & 7) * 8;
            const float* s = Ab + (size_t)(bm0 + m) * NC + k0 + ks;
            float4 v0 = *(const float4*)s;
            float4 v1 = *(const float4*)(s + 4);
            float xs[8] = {v0.x, v0.y, v0.z, v0.w, v1.x, v1.y, v1.z, v1.w};
            half8 hi, lo;
            #pragma unroll
            for (int j = 0; j < 8; ++j) {
                _Float16 h = (_Float16)xs[j];
                hi[j] = h;
                lo[j] = (_Float16)(xs[j] - (float)h);
            }
            int o = (m * 128 + ks * 2) ^ ((m & 7) << 4);
            *(half8*)(lds + AH + o) = hi;
            *(half8*)(lds + AL + o) = lo;
        }
        // ---- stage B tile [64 k][128 n] -> Bs[n][k] hi/lo (transpose, swizzled) ----
        #pragma unroll
        for (int p = 0; p < 4; ++p) {
            int f = p * 256 + tid;
            int n = f & 127, kg = (f >> 7) * 8;
            const float* s = Bb + (size_t)(k0 + kg) * NC + bn0 + n;
            float xs[8];
            #pragma unroll
            for (int i = 0; i < 8; ++i) xs[i] = s[(size_t)i * NC];
            half8 hi, lo;
            #pragma unroll
            for (int j = 0; j < 8; ++j) {
                _Float16 h = (_Float16)xs[j];
                hi[j] = h;
                lo[j] = (_Float16)(xs[j] - (float)h);
            }
            int o = (n * 128 + kg * 2) ^ ((n & 7) << 4);
            *(half8*)(lds + BH + o) = hi;
            *(half8*)(lds + BL + o) = lo;
        }
        __syncthreads();
        // ---- compute: 2 k-steps of 32 ----
        #pragma unroll
        for (int ks = 0; ks < 64; ks += 32) {
            half8 ah[4], bh[4], al[4], bl[4];
            #pragma unroll
            for (int mi = 0; mi < 4; ++mi) {
                int row = wm + mi * 16 + lr;
                int o = (row * 128 + (ks + lk) * 2) ^ ((row & 7) << 4);
                ah[mi] = *(const half8*)(lds + AH + o);
            }
            #pragma unroll
            for (int ni = 0; ni < 4; ++ni) {
                int row = wn + ni * 16 + lr;
                int o = (row * 128 + (ks + lk) * 2) ^ ((row & 7) << 4);
                bh[ni] = *(const half8*)(lds + BH + o);
            }
            #pragma unroll
            for (int mi = 0; mi < 4; ++mi)
                #pragma unroll
                for (int ni = 0; ni < 4; ++ni)
                    acc[mi][ni] = __builtin_amdgcn_mfma_f32_16x16x32_f16(ah[mi], bh[ni], acc[mi][ni], 0, 0, 0);
            #pragma unroll
            for (int ni = 0; ni < 4; ++ni) {
                int row = wn + ni * 16 + lr;
                int o = (row * 128 + (ks + lk) * 2) ^ ((row & 7) << 4);
                bl[ni] = *(const half8*)(lds + BL + o);
            }
            #pragma unroll
            for (int mi = 0; mi < 4; ++mi)
                #pragma unroll
                for (int ni = 0; ni < 4; ++ni)
                    acc[mi][ni] = __builtin_amdgcn_mfma_f32_16x16x32_f16(ah[mi], bl[ni], acc[mi][ni], 0, 0, 0);
            #pragma unroll
            for (int mi = 0; mi < 4; ++mi) {
                int row = wm + mi * 16 + lr;
                int o = (row * 128 + (ks + lk) * 2) ^ ((row & 7) << 4);
                al[mi] = *(const half8*)(lds + AL + o);
            }
            #pragma unroll
            for (int mi = 0; mi < 4; ++mi)
                #pragma unroll
                for (int ni = 0; ni < 4; ++ni)
                    acc[mi][ni] = __builtin_amdgcn_mfma_f32_16x16x32_f16(al[mi], bh[ni], acc[mi][ni], 0, 0, 0);
        }
    }
    // ---- epilogue ----
    float sc = alpha * (scaleA ? scaleA[b] : 1.0f);
    #pragma unroll
    for (int mi = 0; mi < 4; ++mi) {
        #pragma unroll
        for (int ni = 0; ni < 4; ++ni) {
            #pragma unroll
            for (int r = 0; r < 4; ++r) {
                int gr = bm0 + wm + mi * 16 + (l >> 4) * 4 + r;
                int gc = bn0 + wn + ni * 16 + (l & 15);
                size_t o = bofs + (size_t)gr * NC + gc;
                float v = acc[mi][ni][r] * sc;
                if (gr == gc) v += gamma;
                if (M1) v = fmaf(b1, M1[o], v);
                if (M2) v = fmaf(b2, M2[o], v);
                C[o] = v;
            }
        }
    }
}

// ---------------- trace -> 1/tr and sqrt(tr) ----------------
__global__ __launch_bounds__(256) void trace_kernel(const float* __restrict__ C,
                                                    float* __restrict__ rnorm,
                                                    float* __restrict__ snorm) {
    int b = blockIdx.x;
    int tid = threadIdx.x;
    float v = C[(size_t)b * MAT + (size_t)tid * NC + tid];
    for (int off = 32; off; off >>= 1) v += __shfl_down(v, off);
    __shared__ float red[4];
    if ((tid & 63) == 0) red[tid >> 6] = v;
    __syncthreads();
    if (tid == 0) {
        float tr = red[0] + red[1] + red[2] + red[3];
        rnorm[b] = 1.0f / tr;
        snorm[b] = sqrtf(tr);
    }
}

// ---------------- 1/sqrt(clip(diag,eps)) ----------------
__global__ __launch_bounds__(256) void istd_kernel(const float* __restrict__ S,
                                                   float* __restrict__ istd) {
    int b = blockIdx.x;
    int tid = threadIdx.x;
    float d = S[(size_t)b * MAT + (size_t)tid * NC + tid];
    d = fmaxf(d, 1.1920929e-7f);
    istd[b * NC + tid] = 1.0f / sqrtf(d);
}

// ---------------- out = 1.5*I - 0.5*scale_b*in ----------------
__global__ __launch_bounds__(256) void ew_z1_kernel(const float* __restrict__ in,
                                                    float* __restrict__ out,
                                                    const float* __restrict__ scale) {
    size_t idx = (size_t)blockIdx.x * 256 + threadIdx.x;
    int b = (int)(idx >> 16);
    int ij = (int)(idx & 65535);
    float sc = scale ? scale[b] : 1.0f;
    float v = -0.5f * sc * in[idx];
    if ((ij >> 8) == (ij & 255)) v += 1.5f;
    out[idx] = v;
}

// ---------------- out = in * istd_i * istd_j * (1/1.2) ----------------
__global__ __launch_bounds__(256) void ew_corr_kernel(const float* __restrict__ in,
                                                      float* __restrict__ out,
                                                      const float* __restrict__ istd) {
    size_t idx = (size_t)blockIdx.x * 256 + threadIdx.x;
    int b = (int)(idx >> 16);
    int ij = (int)(idx & 65535);
    int i = ij >> 8, j = ij & 255;
    out[idx] = in[idx] * istd[b * NC + i] * istd[b * NC + j] * (1.0f / 1.2f);
}

// ---------------- out = a*X + b*Y ----------------
__global__ __launch_bounds__(256) void ew_axpy2_kernel(const float* __restrict__ X,
                                                       const float* __restrict__ Y,
                                                       float* __restrict__ out,
                                                       float a, float b) {
    size_t idx = (size_t)blockIdx.x * 256 + threadIdx.x;
    out[idx] = fmaf(a, X[idx], b * Y[idx]);
}

// ---------------- W[b,i,i] -= 1 ----------------
__global__ __launch_bounds__(256) void subdiag_kernel(float* __restrict__ W) {
    W[(size_t)blockIdx.x * MAT + (size_t)threadIdx.x * NC + threadIdx.x] -= 1.0f;
}

// ---------------- triuvec output ----------------
__global__ __launch_bounds__(256) void out_kernel(const float* __restrict__ R,
                                                  float* __restrict__ out) {
    int blk = blockIdx.x;
    int b = blk >> 8, r = blk & 255;
    int c = threadIdx.x;
    if (c < r) return;
    size_t rowoff = (size_t)r * NC - ((size_t)r * (r - 1)) / 2;
    float v = (c == r) ? 0.f : 4.f * R[(size_t)b * MAT + (size_t)r * NC + c];
    out[(size_t)b * 32896 + rowoff + (c - r)] = v;
}

extern "C" void kernel_launch(void* const* d_in, const int* in_sizes, int n_in,
                              void* d_out, int out_size, void* d_ws, size_t ws_size,
                              hipStream_t stream) {
    const float* x = (const float*)d_in[0];
    float* out = (float*)d_out;
    float* W0 = (float*)d_ws;
    float* W1 = W0 + MATB;
    float* W2 = W1 + MATB;
    float* W3 = W2 + MATB;
    float* mean  = W3 + MATB;
    float* istd  = mean + NB * NC;
    float* rnorm = istd + NB * NC;
    float* snorm = rnorm + NB;

    const int EWG = (int)(MATB / 256);

    auto GEMM = [&](const float* A, const float* B, float* C, const float* sA,
                    float alpha, float gamma, const float* M1 = nullptr, float b1 = 0.f,
                    const float* M2 = nullptr, float b2 = 0.f) {
        mfma_bgemm_kernel<<<NB * 4, 256, 0, stream>>>(A, B, C, sA, alpha, gamma, M1, b1, M2, b2);
    };

    // ---- covariance pooling ----
    mean_kernel<<<NB * NC, 256, 0, stream>>>(x, mean);
    cov_kernel<<<NB * 16, 256, 0, stream>>>(x, mean, W0);
    trace_kernel<<<NB, 256, 0, stream>>>(W0, rnorm, snorm);

    // ---- reference NS5 sqrt (trace-normalized, 5 iterations) ----
    ew_z1_kernel<<<EWG, 256, 0, stream>>>(W0, W1, rnorm);       // Z1 -> W1
    GEMM(W0, W1, W2, rnorm, 1.f, 0.f);                          // Y1 -> W2
    GEMM(W1, W2, W3, nullptr, -0.5f, 1.5f);                     // T -> W3
    GEMM(W2, W3, W0, nullptr, 1.f, 0.f);                        // Y -> W0
    GEMM(W3, W1, W2, nullptr, 1.f, 0.f);                        // Z -> W2
    GEMM(W2, W0, W1, nullptr, -0.5f, 1.5f);
    GEMM(W0, W1, W3, nullptr, 1.f, 0.f);
    GEMM(W1, W2, W0, nullptr, 1.f, 0.f);
    GEMM(W0, W3, W1, nullptr, -0.5f, 1.5f);
    GEMM(W3, W1, W2, nullptr, 1.f, 0.f);
    GEMM(W1, W0, W3, nullptr, 1.f, 0.f);
    GEMM(W3, W2, W0, nullptr, -1.f, 3.f);                       // Tf -> W0
    GEMM(W2, W0, W1, snorm, 0.5f, 0.f);                         // s -> W1

    // ---- correlation normalization, safety scale 1/1.2 ----
    istd_kernel<<<NB, 256, 0, stream>>>(W1, istd);
    ew_corr_kernel<<<EWG, 256, 0, stream>>>(W1, W2, istd);      // A0 -> W2

    // ---- NS sqrt of A0, 8 coupled updates ----
    ew_z1_kernel<<<EWG, 256, 0, stream>>>(W2, W0, nullptr);     // Z1 -> W0
    GEMM(W2, W0, W1, nullptr, 1.f, 0.f);                        // Y1 -> W1   (Y=W1,Z=W0)
    GEMM(W0, W1, W2, nullptr, -0.5f, 1.5f);
    GEMM(W1, W2, W3, nullptr, 1.f, 0.f);
    GEMM(W2, W0, W1, nullptr, 1.f, 0.f);                        // (Y=W3,Z=W1)
    GEMM(W1, W3, W0, nullptr, -0.5f, 1.5f);
    GEMM(W3, W0, W2, nullptr, 1.f, 0.f);
    GEMM(W0, W1, W3, nullptr, 1.f, 0.f);                        // (Y=W2,Z=W3)
    GEMM(W3, W2, W0, nullptr, -0.5f, 1.5f);
    GEMM(W2, W0, W1, nullptr, 1.f, 0.f);
    GEMM(W0, W3, W2, nullptr, 1.f, 0.f);                        // (Y=W1,Z=W2)
    GEMM(W2, W1, W0, nullptr, -0.5f, 1.5f);
    GEMM(W1, W0, W3, nullptr, 1.f, 0.f);
    GEMM(W0, W2, W1, nullptr, 1.f, 0.f);                        // (Y=W3,Z=W1)
    GEMM(W1, W3, W0, nullptr, -0.5f, 1.5f);
    GEMM(W3, W0, W2, nullptr, 1.f, 0.f);
    GEMM(W0, W1, W3, nullptr, 1.f, 0.f);                        // (Y=W2,Z=W3)
    GEMM(W3, W2, W0, nullptr, -0.5f, 1.5f);
    GEMM(W2, W0, W1, nullptr, 1.f, 0.f);
    GEMM(W0, W3, W2, nullptr, 1.f, 0.f);                        // (Y=W1,Z=W2)
    GEMM(W2, W1, W0, nullptr, -0.5f, 1.5f);                     // T -> W0
    GEMM(W1, W0, W3, nullptr, 1.f, 0.f);                        // C1 -> W3

    // ---- log(C1) = log(I+E), degree-16 Mercator via Paterson-Stockmeyer ----
    subdiag_kernel<<<NB, 256, 0, stream>>>(W3);                 // E -> W3
    GEMM(W3, W3, W0, nullptr, 1.f, 0.f);                        // E2 -> W0
    ew_axpy2_kernel<<<EWG, 256, 0, stream>>>(W3, W0, W1, 1.f / 15.f, -1.f / 16.f);
    GEMM(W1, W0, W2, nullptr, 1.f, 0.f, W3, 1.f / 13.f, W0, -1.f / 14.f);
    GEMM(W2, W0, W1, nullptr, 1.f, 0.f, W3, 1.f / 11.f, W0, -1.f / 12.f);
    GEMM(W1, W0, W2, nullptr, 1.f, 0.f, W3, 1.f / 9.f,  W0, -1.f / 10.f);
    GEMM(W2, W0, W1, nullptr, 1.f, 0.f, W3, 1.f / 7.f,  W0, -1.f / 8.f);
    GEMM(W1, W0, W2, nullptr, 1.f, 0.f, W3, 1.f / 5.f,  W0, -1.f / 6.f);
    GEMM(W2, W0, W1, nullptr, 1.f, 0.f, W3, 1.f / 3.f,  W0, -1.f / 4.f);
    GEMM(W1, W0, W2, nullptr, 1.f, 0.f, W3, 1.f,        W0, -1.f / 2.f);  // log(C1) -> W2

    // ---- output ----
    out_kernel<<<NB * NC, 256, 0, stream>>>(W2, out);
}